// Round 8
// baseline (434.188 us; speedup 1.0000x reference)
//
#include <hip/hip_runtime.h>
#include <cstdint>
#include <cstddef>

// ---------- types ----------
typedef _Float16 f16;
typedef __attribute__((ext_vector_type(8))) _Float16 f16x8;
typedef __attribute__((ext_vector_type(4))) _Float16 f16x4;
typedef __attribute__((ext_vector_type(4))) float    f32x4;
typedef __attribute__((ext_vector_type(8))) __bf16   bf16x8;
typedef __attribute__((ext_vector_type(4))) __bf16   bf16x4;

typedef __attribute__((address_space(1))) const uint32_t gu32;
typedef __attribute__((address_space(3))) uint32_t       lu32;

__device__ __forceinline__ void gload16(const void* g, void* l) {
    // async global->LDS, 16B per lane; LDS dest is wave-uniform base + lane*16
    __builtin_amdgcn_global_load_lds((gu32*)g, (lu32*)l, 16, 0, 0);
}

// hole slots: upper-triangle region of scores[b=0], rows 0..39, cols 1024..2047.
// Causal QK never writes there (tiles bj>bi skipped) and softmax never reads
// cols >= Vs(row)=128 for those rows. slots j<40960: j>>10 = row, 1024+(j&1023) = col.
__device__ __forceinline__ float* hole(float* sc, int j) {
    return sc + ((size_t)(j >> 10) * 2048 + 1024 + (j & 1023));
}
__device__ __forceinline__ const float* holec(const float* sc, int j) {
    return sc + ((size_t)(j >> 10) * 2048 + 1024 + (j & 1023));
}

// ---------- conversion: f32 -> fp16 hi/lo planes ----------
__global__ __launch_bounds__(256)
void split_f32_to_f16(const float* __restrict__ in, f16* __restrict__ h,
                      f16* __restrict__ l, int n4)
{
    int i = blockIdx.x * blockDim.x + threadIdx.x;
    const int stride = gridDim.x * blockDim.x;
    for (; i < n4; i += stride) {
        float4 x = ((const float4*)in)[i];
        f16x4 hv, lv;
        hv[0] = (f16)x.x; lv[0] = (f16)(x.x - (float)hv[0]);
        hv[1] = (f16)x.y; lv[1] = (f16)(x.y - (float)hv[1]);
        hv[2] = (f16)x.z; lv[2] = (f16)(x.z - (float)hv[2]);
        hv[3] = (f16)x.w; lv[3] = (f16)(x.w - (float)hv[3]);
        ((f16x4*)h)[i] = hv;
        ((f16x4*)l)[i] = lv;
    }
}

// ---------- suffix sums of V along t: suffVT[b][s][d] = sum_{t>s} V[b][d][t] ----------
__global__ __launch_bounds__(256)
void suffv_pass1(const float* __restrict__ V, float* __restrict__ holes)
{
    const int d = blockIdx.x * 256 + threadIdx.x;   // 0..1023
    const int c = blockIdx.y, b = blockIdx.z;       // chunk 0..7, batch
    const float* v = V + ((size_t)b * 1024 + d) * 2048 + c * 256;
    float s = 0.f;
    #pragma unroll 8
    for (int i = 0; i < 256; ++i) s += v[i];
    *hole(holes, 8192 + ((b * 1024 + d) * 8 + c)) = s;   // partials at slots [8192,40960)
}

__global__ __launch_bounds__(256)
void suffv_pass2(const float* __restrict__ V, const float* __restrict__ holes,
                 float* __restrict__ suffVT)
{
    const int d = blockIdx.x * 256 + threadIdx.x;
    const int c = blockIdx.y, b = blockIdx.z;
    float acc = 0.f;
    for (int cc = c + 1; cc < 8; ++cc)
        acc += *holec(holes, 8192 + ((b * 1024 + d) * 8 + cc));
    const float* v = V + ((size_t)b * 1024 + d) * 2048;
    float* o = suffVT + (size_t)b * 2048 * 1024 + d;      // [b][s][d]
    for (int s = c * 256 + 255; s >= c * 256; --s) {
        o[(size_t)s * 1024] = acc;    // coalesced across threads (consecutive d)
        acc += v[s];
    }
}

// ---------- fp16 split GEMM (bt form), 2-phase double-buffered staging ----------
// C[m,n] = sum_k A[m,k]*B[n,k]. 128x128 tile, BK=32, 4 waves of 64x64.
// NA/NB: planes per operand. Terms: Ah*Bh [+ Al*Bh] [+ Ah*Bl].
// OUTK: 0 = f32 (+bias), 2 = fp16 hi/lo pair.
// MODE: 0 dense; 1 causal-QK (triangular grid); 2 causal-PV (K limited to
//       (bm+1)*128, epilogue adds cmask[row]*suffVT[row][col]).
template<int NA, int NB, int OUTK, int MODE>
__global__ __launch_bounds__(256)
void gemm2(const f16* __restrict__ Ah, const f16* __restrict__ Al, int lda, size_t sA,
           const f16* __restrict__ Bh, const f16* __restrict__ Bl, int ldb, size_t sB,
           void* __restrict__ Cv, void* __restrict__ Cl2, int ldc, size_t sC, int Kfull,
           const float* __restrict__ bias,
           const float* __restrict__ holes, const float* __restrict__ suffVT)
{
    constexpr int NP = NA + NB;
    __shared__ __attribute__((aligned(16))) f16 smem[2][NP * 4096];

    int bm, bn;
    if constexpr (MODE == 1) {
        int t = blockIdx.x;
        int bi = (int)((sqrtf(8.0f * (float)t + 1.0f) - 1.0f) * 0.5f);
        while ((bi + 1) * (bi + 2) / 2 <= t) ++bi;
        while (bi * (bi + 1) / 2 > t) --bi;
        bm = bi; bn = t - bi * (bi + 1) / 2;
    } else { bm = blockIdx.y; bn = blockIdx.x; }
    const int m0 = bm * 128, n0 = bn * 128;

    const int K  = (MODE == 2) ? (bm + 1) * 128 : Kfull;
    const int NT = K >> 5;

    const int tid = threadIdx.x, lane = tid & 63, w = tid >> 6;
    const f16* Ab  = Ah + sA * blockIdx.z + (size_t)m0 * lda;
    const f16* Alb = (NA > 1) ? Al + sA * blockIdx.z + (size_t)m0 * lda : nullptr;
    const f16* Bb  = Bh + sB * blockIdx.z + (size_t)n0 * ldb;
    const f16* Blb = (NB > 1) ? Bl + sB * blockIdx.z + (size_t)n0 * ldb : nullptr;

    const int srow = lane >> 2;        // row within 16-row chunk
    const int scol = (lane & 3) * 8;   // col granule (16B)
    const int wm = (w >> 1) * 64, wn = (w & 1) * 64;
    const int fr = lane & 15, koff = (lane >> 4) * 8;

    f32x4 acc[4][4] = {};

    auto STAGE = [&](int buf, int k0) {
        f16* sm = &smem[buf][0];
        #pragma unroll
        for (int j = 0; j < 2; ++j) {
            const int ch = w * 2 + j;
            const int r  = ch * 16 + srow;
            const int lo = ch * 512;
            gload16(Ab + (size_t)r * lda + (k0 + scol), sm + lo);
            if constexpr (NA > 1) gload16(Alb + (size_t)r * lda + (k0 + scol), sm + 4096 + lo);
            gload16(Bb + (size_t)r * ldb + (k0 + scol), sm + NA * 4096 + lo);
            if constexpr (NB > 1) gload16(Blb + (size_t)r * ldb + (k0 + scol), sm + (NA + 1) * 4096 + lo);
        }
    };

    // 2-phase: stage(t+1) issued before compute(t); __syncthreads()' implicit
    // vmcnt(0)+lgkmcnt(0) drain at iteration end completes next tile's loads
    // (hidden under MFMA) and protects buffer reuse (buf written at t+1 was
    // last read at t-1, all waves past the barrier).
    STAGE(0, 0);
    __syncthreads();
    for (int t = 0; t < NT; ++t) {
        const int cur = t & 1;
        if (t + 1 < NT) STAGE(cur ^ 1, (t + 1) << 5);
        const f16* sm = &smem[cur][0];
        f16x8 a_h[4], a_l[4], b_h[4], b_l[4];
        #pragma unroll
        for (int mi = 0; mi < 4; ++mi) {
            const int r = wm + mi * 16 + fr;
            a_h[mi] = *(const f16x8*)&sm[r * 32 + koff];
            if constexpr (NA > 1) a_l[mi] = *(const f16x8*)&sm[4096 + r * 32 + koff];
        }
        #pragma unroll
        for (int ni = 0; ni < 4; ++ni) {
            const int r = wn + ni * 16 + fr;
            b_h[ni] = *(const f16x8*)&sm[NA * 4096 + r * 32 + koff];
            if constexpr (NB > 1) b_l[ni] = *(const f16x8*)&sm[(NA + 1) * 4096 + r * 32 + koff];
        }
        #pragma unroll
        for (int mi = 0; mi < 4; ++mi) {
            #pragma unroll
            for (int ni = 0; ni < 4; ++ni) {
                acc[mi][ni] = __builtin_amdgcn_mfma_f32_16x16x32_f16(a_h[mi], b_h[ni], acc[mi][ni], 0, 0, 0);
                if constexpr (NA > 1)
                    acc[mi][ni] = __builtin_amdgcn_mfma_f32_16x16x32_f16(a_l[mi], b_h[ni], acc[mi][ni], 0, 0, 0);
                if constexpr (NB > 1)
                    acc[mi][ni] = __builtin_amdgcn_mfma_f32_16x16x32_f16(a_h[mi], b_l[ni], acc[mi][ni], 0, 0, 0);
            }
        }
        __syncthreads();
    }

    // epilogue: C/D layout col=lane&15, row=(lane>>4)*4+reg [m89-verified]
    const int rbase = (lane >> 4) * 4, ccol = lane & 15;

    if constexpr (MODE == 2) {
        // masked-weight contribution: cmask[row] * suffVT[b][row][col] (f32-exact)
        const size_t sb = (size_t)blockIdx.z * 2048 * 1024;
        #pragma unroll
        for (int mi = 0; mi < 4; ++mi)
            #pragma unroll
            for (int r = 0; r < 4; ++r) {
                const int rowg = m0 + wm + mi * 16 + rbase + r;
                const float cm = *holec(holes, (int)blockIdx.z * 2048 + rowg);
                const float* sv = suffVT + sb + (size_t)rowg * 1024;
                #pragma unroll
                for (int ni = 0; ni < 4; ++ni)
                    acc[mi][ni][r] += cm * sv[n0 + wn + ni * 16 + ccol];
            }
    }

    if constexpr (OUTK == 0) {
        float* C = (float*)Cv + sC * blockIdx.z;
        #pragma unroll
        for (int ni = 0; ni < 4; ++ni) {
            const int col = n0 + wn + ni * 16 + ccol;
            const float bv = bias ? bias[col] : 0.0f;
            #pragma unroll
            for (int mi = 0; mi < 4; ++mi)
                #pragma unroll
                for (int r = 0; r < 4; ++r)
                    C[(size_t)(m0 + wm + mi * 16 + rbase + r) * ldc + col] = acc[mi][ni][r] + bv;
        }
    } else {
        f16* Ch = (f16*)Cv  + sC * blockIdx.z;
        f16* Cl = (f16*)Cl2 + sC * blockIdx.z;
        #pragma unroll
        for (int ni = 0; ni < 4; ++ni) {
            const int col = n0 + wn + ni * 16 + ccol;
            #pragma unroll
            for (int mi = 0; mi < 4; ++mi)
                #pragma unroll
                for (int r = 0; r < 4; ++r) {
                    const size_t idx = (size_t)(m0 + wm + mi * 16 + rbase + r) * ldc + col;
                    const float x = acc[mi][ni][r];
                    const f16 h = (f16)x;
                    Ch[idx] = h;
                    Cl[idx] = (f16)(x - (float)h);
                }
        }
    }
}

// ---------- softmax -> triangular fp16 P + cmask ----------
// real (t<=s): exp(x/32+1e-13-m)/Z ; in-tile masked (s<t<Vs): 0 (handled by
// suffix correction) ; beyond Vs: unwritten/unread. cmask[b,s]=exp(-1e-13-m)/Z.
__global__ __launch_bounds__(256)
void softmax_p2(const float* __restrict__ scores, f16* __restrict__ P,
                float* __restrict__ holes)
{
    const int s = blockIdx.x, b = blockIdx.y;
    const float* srow = scores + ((size_t)b * 2048 + s) * 2048;
    f16* prow = P + ((size_t)b * 2048 + s) * 2048;
    const int tid = threadIdx.x, c0 = tid * 8;
    const int Vs = ((s >> 7) + 1) << 7;
    const int lane = tid & 63, wv = tid >> 6;

    float v[8];
    const bool have = c0 < Vs;
    float mloc = -3.4e38f;
    if (have) {
        float4 x0 = *(const float4*)(srow + c0);
        float4 x1 = *(const float4*)(srow + c0 + 4);
        const float xs[8] = {x0.x, x0.y, x0.z, x0.w, x1.x, x1.y, x1.z, x1.w};
        #pragma unroll
        for (int j = 0; j < 8; ++j) {
            const int col = c0 + j;
            if (col <= s) { v[j] = fmaf(xs[j], 0.03125f, 1e-13f); mloc = fmaxf(mloc, v[j]); }
            else v[j] = 0.0f;
        }
    }
    #pragma unroll
    for (int off = 1; off < 64; off <<= 1) mloc = fmaxf(mloc, __shfl_xor(mloc, off));
    __shared__ float redm[4], redz[4];
    if (lane == 0) redm[wv] = mloc;
    __syncthreads();
    float m = fmaxf(fmaxf(redm[0], redm[1]), fmaxf(redm[2], redm[3]));
    if (s < 2047) m = fmaxf(m, -1e-13f);  // masked entries participate in max

    float zloc = 0.0f;
    if (have) {
        #pragma unroll
        for (int j = 0; j < 8; ++j) {
            const int col = c0 + j;
            if (col <= s) { v[j] = expf(v[j] - m); zloc += v[j]; }
        }
    }
    #pragma unroll
    for (int off = 1; off < 64; off <<= 1) zloc += __shfl_xor(zloc, off);
    if (lane == 0) redz[wv] = zloc;
    __syncthreads();
    const float em = expf(-1e-13f - m);
    const float Z = redz[0] + redz[1] + redz[2] + redz[3] + (float)(2047 - s) * em;
    const float inv = 1.0f / Z;

    if (have) {
        f16x8 outv;
        #pragma unroll
        for (int j = 0; j < 8; ++j) {
            const int col = c0 + j;
            outv[j] = (col <= s) ? (f16)(v[j] * inv) : (f16)0.0f;
        }
        *(f16x8*)(prow + c0) = outv;
    }
    if (tid == 0) *hole(holes, b * 2048 + s) = em * inv;
}

// ================== fallback kernels (f32 in, bf16 split, reg-staged) ==================
__device__ __forceinline__ void split4b(const float4 v, bf16x4& h, bf16x4& l) {
    __bf16 h0 = (__bf16)v.x; float r0 = v.x - (float)h0;
    __bf16 h1 = (__bf16)v.y; float r1 = v.y - (float)h1;
    __bf16 h2 = (__bf16)v.z; float r2 = v.z - (float)h2;
    __bf16 h3 = (__bf16)v.w; float r3 = v.w - (float)h3;
    h[0] = h0; h[1] = h1; h[2] = h2; h[3] = h3;
    l[0] = (__bf16)r0; l[1] = (__bf16)r1; l[2] = (__bf16)r2; l[3] = (__bf16)r3;
}

__global__ __launch_bounds__(256)
void gemm_bt_split(const float* __restrict__ A, int lda, size_t strideA,
                   const float* __restrict__ B, int ldb, size_t strideB,
                   float* __restrict__ C, int ldc, size_t strideC,
                   int K, const float* __restrict__ bias)
{
    constexpr int LDT = 48;
    __shared__ __attribute__((aligned(16))) __bf16 Ah[128 * LDT];
    __shared__ __attribute__((aligned(16))) __bf16 Al[128 * LDT];
    __shared__ __attribute__((aligned(16))) __bf16 Bh[128 * LDT];
    __shared__ __attribute__((aligned(16))) __bf16 Bl[128 * LDT];
    const int tid = threadIdx.x;
    const int m0 = blockIdx.y * 128, n0 = blockIdx.x * 128;
    const float* Ab = A + strideA * blockIdx.z + (size_t)m0 * lda;
    const float* Bb = B + strideB * blockIdx.z + (size_t)n0 * ldb;
    const int lane = tid & 63, wid = tid >> 6;
    const int wm = (wid >> 1) * 64, wn = (wid & 1) * 64;
    const int fr = lane & 15, koff = (lane >> 4) << 3;
    f32x4 acc[4][4] = {};
    for (int k0 = 0; k0 < K; k0 += 32) {
        __syncthreads();
        #pragma unroll
        for (int i = 0; i < 4; ++i) {
            int f4 = tid + 256 * i, row = f4 >> 3, c4 = (f4 & 7) << 2;
            float4 va = *(const float4*)(Ab + (size_t)row * lda + (k0 + c4));
            bf16x4 h, l; split4b(va, h, l);
            *(bf16x4*)&Ah[row * LDT + c4] = h; *(bf16x4*)&Al[row * LDT + c4] = l;
            float4 vb = *(const float4*)(Bb + (size_t)row * ldb + (k0 + c4));
            split4b(vb, h, l);
            *(bf16x4*)&Bh[row * LDT + c4] = h; *(bf16x4*)&Bl[row * LDT + c4] = l;
        }
        __syncthreads();
        bf16x8 ah[4], al[4], bh[4], bl[4];
        #pragma unroll
        for (int mi = 0; mi < 4; ++mi) {
            int r = wm + mi * 16 + fr;
            ah[mi] = *(const bf16x8*)&Ah[r * LDT + koff];
            al[mi] = *(const bf16x8*)&Al[r * LDT + koff];
        }
        #pragma unroll
        for (int ni = 0; ni < 4; ++ni) {
            int r = wn + ni * 16 + fr;
            bh[ni] = *(const bf16x8*)&Bh[r * LDT + koff];
            bl[ni] = *(const bf16x8*)&Bl[r * LDT + koff];
        }
        #pragma unroll
        for (int mi = 0; mi < 4; ++mi)
            #pragma unroll
            for (int ni = 0; ni < 4; ++ni) {
                acc[mi][ni] = __builtin_amdgcn_mfma_f32_16x16x32_bf16(ah[mi], bh[ni], acc[mi][ni], 0, 0, 0);
                acc[mi][ni] = __builtin_amdgcn_mfma_f32_16x16x32_bf16(al[mi], bh[ni], acc[mi][ni], 0, 0, 0);
                acc[mi][ni] = __builtin_amdgcn_mfma_f32_16x16x32_bf16(ah[mi], bl[ni], acc[mi][ni], 0, 0, 0);
            }
    }
    float* Cb = C + strideC * blockIdx.z;
    const int rbase = (lane >> 4) * 4, ccol = lane & 15;
    #pragma unroll
    for (int ni = 0; ni < 4; ++ni) {
        int col = n0 + wn + ni * 16 + ccol;
        float bv = bias ? bias[col] : 0.0f;
        #pragma unroll
        for (int mi = 0; mi < 4; ++mi)
            #pragma unroll
            for (int r = 0; r < 4; ++r)
                Cb[(size_t)(m0 + wm + mi * 16 + rbase + r) * ldc + col] = acc[mi][ni][r] + bv;
    }
}

__global__ __launch_bounds__(256)
void softmax_causal(float* __restrict__ P, int S)
{
    const int row = blockIdx.x;
    float* p = P + ((size_t)blockIdx.y * S + row) * (size_t)S;
    const int tid = threadIdx.x, lane = tid & 63, wid = tid >> 6;
    float v[8];
    float4 x0 = *(const float4*)(p + tid * 4);
    float4 x1 = *(const float4*)(p + 1024 + tid * 4);
    const float xs[8] = {x0.x, x0.y, x0.z, x0.w, x1.x, x1.y, x1.z, x1.w};
    #pragma unroll
    for (int j = 0; j < 8; ++j) {
        int col = (j < 4) ? (tid * 4 + j) : (1024 + tid * 4 + (j - 4));
        v[j] = (col > row) ? -1e-13f : fmaf(xs[j], 0.03125f, 1e-13f);
    }
    float m = v[0];
    #pragma unroll
    for (int j = 1; j < 8; ++j) m = fmaxf(m, v[j]);
    #pragma unroll
    for (int off = 1; off < 64; off <<= 1) m = fmaxf(m, __shfl_xor(m, off));
    __shared__ float red[8];
    if (lane == 0) red[wid] = m;
    __syncthreads();
    m = fmaxf(fmaxf(red[0], red[1]), fmaxf(red[2], red[3]));
    float sm = 0.0f;
    #pragma unroll
    for (int j = 0; j < 8; ++j) { v[j] = expf(v[j] - m); sm += v[j]; }
    #pragma unroll
    for (int off = 1; off < 64; off <<= 1) sm += __shfl_xor(sm, off);
    if (lane == 0) red[4 + wid] = sm;
    __syncthreads();
    sm = red[4] + red[5] + red[6] + red[7];
    const float inv = 1.0f / sm;
    float4 o0, o1;
    o0.x = v[0] * inv; o0.y = v[1] * inv; o0.z = v[2] * inv; o0.w = v[3] * inv;
    o1.x = v[4] * inv; o1.y = v[5] * inv; o1.z = v[6] * inv; o1.w = v[7] * inv;
    *(float4*)(p + tid * 4) = o0;
    *(float4*)(p + 1024 + tid * 4) = o1;
}

// ---------- launch ----------
extern "C" void kernel_launch(void* const* d_in, const int* in_sizes, int n_in,
                              void* d_out, int out_size, void* d_ws, size_t ws_size,
                              hipStream_t stream)
{
    const float* Q  = (const float*)d_in[0];   // [B,S,D]
    const float* Km = (const float*)d_in[1];   // [B,S,D]
    const float* V  = (const float*)d_in[2];   // [B,D,S]
    const float* W  = (const float*)d_in[3];   // [E,D]
    const float* bv = (const float*)d_in[4];   // [E]
    float* out = (float*)d_out;                // [B,S,E]

    constexpr int B = 4, S = 2048, D = 1024, E = 1024;
    const dim3 blk(256);
    const size_t MB = 1u << 20;

    if (ws_size >= 164 * MB) {
        char* w8 = (char*)d_ws;
        float* scores = (float*)w8;                       // [0,64)MB f32 (holes: cmask+partials)
        f16* attn_h   = (f16*)(w8 + 32 * MB);             // [32,48) over dead scores (no hole overlap)
        f16* attn_l   = (f16*)(w8 + 48 * MB);             // [48,64)
        f16* Qh = (f16*)(w8 + 64 * MB);                   // [64,80)
        f16* Ql = (f16*)(w8 + 80 * MB);                   // [80,96)
        f16* P  = (f16*)(w8 + 64 * MB);                   // [64,96) overlays Qh/Ql (dead after QK)
        f16* Kh = (f16*)(w8 + 96 * MB);
        f16* Kl = (f16*)(w8 + 112 * MB);
        float* suffVT = (float*)(w8 + 96 * MB);           // [96,128) overlays Kh/Kl (dead after QK)
        f16* Vh = (f16*)(w8 + 128 * MB);
        f16* Vl = (f16*)(w8 + 144 * MB);
        f16* Wh = (f16*)(w8 + 160 * MB);                  // 2MB
        f16* Wl = (f16*)(w8 + 162 * MB);                  // 2MB

        split_f32_to_f16<<<2048, blk, 0, stream>>>(Q,  Qh, Ql, B * S * D / 4);
        split_f32_to_f16<<<2048, blk, 0, stream>>>(Km, Kh, Kl, B * S * D / 4);
        split_f32_to_f16<<<2048, blk, 0, stream>>>(V,  Vh, Vl, B * D * S / 4);
        split_f32_to_f16<<<512,  blk, 0, stream>>>(W,  Wh, Wl, E * D / 4);
        suffv_pass1<<<dim3(D / 256, 8, B), blk, 0, stream>>>(V, scores);

        // 1) scores = Q.K^T, lower-triangle tiles only (3-term split)
        constexpr int NTt = S / 128;
        gemm2<2, 2, 0, 1><<<dim3(NTt * (NTt + 1) / 2, 1, B), blk, 0, stream>>>(
            Qh, Ql, D, (size_t)S * D, Kh, Kl, D, (size_t)S * D,
            scores, nullptr, S, (size_t)S * S, D, nullptr, nullptr, nullptr);
        // 2) softmax -> triangular fp16 P + cmask
        softmax_p2<<<dim3(S, B), blk, 0, stream>>>(scores, P, scores);
        // suffix sums (over dead Kh/Kl)
        suffv_pass2<<<dim3(D / 256, 8, B), blk, 0, stream>>>(V, scores, suffVT);
        // 3) attn = P_tri.V^T + cmask*suffV (triangular K; fp16 hi/lo out)
        gemm2<1, 2, 2, 2><<<dim3(D / 128, S / 128, B), blk, 0, stream>>>(
            P, nullptr, S, (size_t)S * S, Vh, Vl, S, (size_t)D * S,
            attn_h, attn_l, D, (size_t)S * D, S, nullptr, scores, suffVT);
        // 4) out = attn.W^T + b (3-term)
        gemm2<2, 2, 0, 0><<<dim3(E / 128, (B * S) / 128, 1), blk, 0, stream>>>(
            attn_h, attn_l, D, 0, Wh, Wl, D, 0, out, nullptr, E, 0, D, bv,
            nullptr, nullptr);
    } else if (ws_size >= ((size_t)B * S * S + (size_t)B * S * D) * sizeof(float)) {
        float* scores = (float*)d_ws;
        float* attn   = scores + (size_t)B * S * S;
        gemm_bt_split<<<dim3(S / 128, S / 128, B), blk, 0, stream>>>(
            Q, D, (size_t)S * D, Km, D, (size_t)S * D, scores, S, (size_t)S * S, D, nullptr);
        softmax_causal<<<dim3(S, B), blk, 0, stream>>>(scores, S);
        gemm_bt_split<<<dim3(D / 128, S / 128, B), blk, 0, stream>>>(
            scores, S, (size_t)S * S, V, S, (size_t)D * S, attn, D, (size_t)S * D, S, nullptr);
        gemm_bt_split<<<dim3(E / 128, (B * S) / 128, 1), blk, 0, stream>>>(
            attn, D, 0, W, D, 0, out, E, 0, D, bv);
    } else {
        float* sc   = (float*)d_ws;
        float* attn = sc + (size_t)S * S;
        for (int b = 0; b < B; ++b) {
            const float* Qb = Q  + (size_t)b * S * D;
            const float* Kb = Km + (size_t)b * S * D;
            const float* Vb = V  + (size_t)b * D * S;
            float* outb = out + (size_t)b * S * E;
            gemm_bt_split<<<dim3(S / 128, S / 128, 1), blk, 0, stream>>>(
                Qb, D, 0, Kb, D, 0, sc, S, 0, D, nullptr);
            softmax_causal<<<dim3(S, 1), blk, 0, stream>>>(sc, S);
            gemm_bt_split<<<dim3(D / 128, S / 128, 1), blk, 0, stream>>>(
                sc, S, 0, Vb, S, 0, attn, D, 0, S, nullptr);
            gemm_bt_split<<<dim3(E / 128, S / 128, 1), blk, 0, stream>>>(
                attn, D, 0, W, D, 0, outb, E, 0, D, bv);
        }
    }
}

// Round 10
// 395.700 us; speedup vs baseline: 1.0973x; 1.0973x over previous
//
#include <hip/hip_runtime.h>
#include <cstdint>
#include <cstddef>

// ---------- types ----------
typedef _Float16 f16;
typedef __attribute__((ext_vector_type(8))) _Float16 f16x8;
typedef __attribute__((ext_vector_type(4))) _Float16 f16x4;
typedef __attribute__((ext_vector_type(4))) float    f32x4;
typedef __attribute__((ext_vector_type(8))) __bf16   bf16x8;
typedef __attribute__((ext_vector_type(4))) __bf16   bf16x4;

typedef __attribute__((address_space(1))) const uint32_t gu32;
typedef __attribute__((address_space(3))) uint32_t       lu32;

__device__ __forceinline__ void gload16(const void* g, void* l) {
    // async global->LDS, 16B per lane; LDS dest is wave-uniform base + lane*16
    __builtin_amdgcn_global_load_lds((gu32*)g, (lu32*)l, 16, 0, 0);
}

// m204 bijective XCD swizzle: contiguous chunks of the linear grid per XCD
__device__ __forceinline__ int xcd_swz(int orig, int nwg) {
    const int q = nwg >> 3, r = nwg & 7;
    const int x = orig & 7, i = orig >> 3;
    return (x < r ? x * (q + 1) : r * (q + 1) + (x - r) * q) + i;
}

// hole slots: upper-triangle region of scores[b=0], rows 0..39, cols 1024..2047.
// QK (bm=0 tile writes only cols <256 there) never writes them; softmax for
// those rows never reads cols >= Vs'=256. slots: j>>10 = row, 1024+(j&1023) = col.
__device__ __forceinline__ float* hole(float* sc, int j) {
    return sc + ((size_t)(j >> 10) * 2048 + 1024 + (j & 1023));
}
__device__ __forceinline__ const float* holec(const float* sc, int j) {
    return sc + ((size_t)(j >> 10) * 2048 + 1024 + (j & 1023));
}

// ---------- conversion: f32 -> fp16 hi/lo planes ----------
__global__ __launch_bounds__(256)
void split_f32_to_f16(const float* __restrict__ in, f16* __restrict__ h,
                      f16* __restrict__ l, int n4)
{
    int i = blockIdx.x * blockDim.x + threadIdx.x;
    const int stride = gridDim.x * blockDim.x;
    for (; i < n4; i += stride) {
        float4 x = ((const float4*)in)[i];
        f16x4 hv, lv;
        hv[0] = (f16)x.x; lv[0] = (f16)(x.x - (float)hv[0]);
        hv[1] = (f16)x.y; lv[1] = (f16)(x.y - (float)hv[1]);
        hv[2] = (f16)x.z; lv[2] = (f16)(x.z - (float)hv[2]);
        hv[3] = (f16)x.w; lv[3] = (f16)(x.w - (float)hv[3]);
        ((f16x4*)h)[i] = hv;
        ((f16x4*)l)[i] = lv;
    }
}

// ---------- suffix sums of V along t: suffVT[b][s][d] = sum_{t>s} V[b][d][t] ----------
__global__ __launch_bounds__(256)
void suffv_pass1(const float* __restrict__ V, float* __restrict__ holes)
{
    const int d = blockIdx.x * 256 + threadIdx.x;
    const int c = blockIdx.y, b = blockIdx.z;
    const float* v = V + ((size_t)b * 1024 + d) * 2048 + c * 256;
    float s = 0.f;
    #pragma unroll 8
    for (int i = 0; i < 256; ++i) s += v[i];
    *hole(holes, 8192 + ((b * 1024 + d) * 8 + c)) = s;
}

__global__ __launch_bounds__(256)
void suffv_pass2(const float* __restrict__ V, const float* __restrict__ holes,
                 float* __restrict__ suffVT)
{
    const int d = blockIdx.x * 256 + threadIdx.x;
    const int c = blockIdx.y, b = blockIdx.z;
    float acc = 0.f;
    for (int cc = c + 1; cc < 8; ++cc)
        acc += *holec(holes, 8192 + ((b * 1024 + d) * 8 + cc));
    const float* v = V + ((size_t)b * 1024 + d) * 2048;
    float* o = suffVT + (size_t)b * 2048 * 1024 + d;
    for (int s = c * 256 + 255; s >= c * 256; --s) {
        o[(size_t)s * 1024] = acc;
        acc += v[s];
    }
}

// ---------- fp16 split GEMM (bt form), 8 waves, asymmetric TMxTN tiles ----------
// C[m,n] = sum_k A[m,k]*B[n,k]. BK=32, 512 threads, wave-tile 64x64,
// wave grid (TM/64) x (TN/64) (product must be 8).
// NA/NB: planes per operand. Terms: Ah*Bh [+ Al*Bh] [+ Ah*Bl].
// OUTK: 0 = f32 (+bias), 2 = fp16 hi/lo pair.
// MODE: 0 dense (swizzled linear grid); 1 causal-QK (triangular x-grid,
//       tiles with bn*TN <= bm*TM+TM-1); 2 causal-PV (K=(bm+1)*TM, epilogue
//       adds cmask[row]*suffVT[row][col]).
template<int NA, int NB, int OUTK, int MODE, int TM, int TN>
__global__ __launch_bounds__(512)
void gemm3(const f16* __restrict__ Ah, const f16* __restrict__ Al, int lda, size_t sA,
           const f16* __restrict__ Bh, const f16* __restrict__ Bl, int ldb, size_t sB,
           void* __restrict__ Cv, void* __restrict__ Cl2, int ldc, size_t sC, int Kfull,
           const float* __restrict__ bias,
           const float* __restrict__ holes, const float* __restrict__ suffVT)
{
    constexpr int TMW = TM / 64, TNW = TN / 64;
    static_assert(TMW * TNW == 8, "8 waves");
    constexpr int ROWS = NA * TM + NB * TN;       // staged rows per K-step
    constexpr int GPT  = ROWS / 128;              // 16B granules per thread
    __shared__ __attribute__((aligned(16))) f16 smem[2][ROWS * 32];

    int bm, bn;
    if constexpr (MODE == 1) {
        int t = xcd_swz(blockIdx.x, gridDim.x);
        bm = 0;
        while (t >= (bm >> 1) + 1) { t -= (bm >> 1) + 1; ++bm; }
        bn = t;
    } else {
        const int lin = xcd_swz(blockIdx.x + gridDim.x * blockIdx.y,
                                gridDim.x * gridDim.y);
        bn = lin % gridDim.x; bm = lin / gridDim.x;
    }
    const int m0 = bm * TM, n0 = bn * TN;
    const int K  = (MODE == 2) ? (bm + 1) * TM : Kfull;
    const int NT = K >> 5;

    const int tid = threadIdx.x, lane = tid & 63, w = tid >> 6;
    const f16* Ab  = Ah + sA * blockIdx.z + (size_t)m0 * lda;
    const f16* Alb = (NA > 1) ? Al + sA * blockIdx.z + (size_t)m0 * lda : nullptr;
    const f16* Bb  = Bh + sB * blockIdx.z + (size_t)n0 * ldb;
    const f16* Blb = (NB > 1) ? Bl + sB * blockIdx.z + (size_t)n0 * ldb : nullptr;

    const int wm = (w / TNW) * 64, wn = (w % TNW) * 64;
    const int fr = lane & 15, koff = (lane >> 4) * 8;

    f32x4 acc[4][4] = {};

    // stage one K-step: ROWS rows x 32 cols fp16, linear LDS fill.
    // granule g = tid + 512*j -> row g>>2, col (g&3)*8; each wave spans 16 rows
    // starting at a multiple of 16; plane boundaries (TM, 2TM, 2TM+TN) are
    // multiples of 16, so waves never straddle planes -> no divergence, and
    // LDS dest = wave-uniform base + lane*16 (global_load_lds contract).
    auto STAGE = [&](int buf, int k0) {
        f16* sm = &smem[buf][0];
        #pragma unroll
        for (int j = 0; j < GPT; ++j) {
            const int g = tid + 512 * j;
            const int r = g >> 2;
            const int c = (g & 3) * 8;
            const f16* src;
            if (r < TM) src = Ab + (size_t)r * lda;
            else if (NA > 1 && r < 2 * TM) src = Alb + (size_t)(r - TM) * lda;
            else {
                const int r2 = r - NA * TM;
                if (NB > 1 && r2 >= TN) src = Blb + (size_t)(r2 - TN) * ldb;
                else src = Bb + (size_t)r2 * ldb;
            }
            gload16(src + k0 + c, sm + (size_t)g * 8);
        }
    };

    // 2-phase: stage(t+1) before compute(t); barrier's vmcnt drain overlaps
    // next-tile loads with this tile's MFMAs.
    STAGE(0, 0);
    __syncthreads();
    for (int t = 0; t < NT; ++t) {
        const int cur = t & 1;
        if (t + 1 < NT) STAGE(cur ^ 1, (t + 1) << 5);
        const f16* sm = &smem[cur][0];
        f16x8 a_h[4], a_l[4], b_h[4], b_l[4];
        #pragma unroll
        for (int mi = 0; mi < 4; ++mi) {
            const int r = wm + mi * 16 + fr;
            a_h[mi] = *(const f16x8*)&sm[r * 32 + koff];
            if constexpr (NA > 1) a_l[mi] = *(const f16x8*)&sm[(TM + r) * 32 + koff];
        }
        #pragma unroll
        for (int ni = 0; ni < 4; ++ni) {
            const int r = wn + ni * 16 + fr;
            b_h[ni] = *(const f16x8*)&sm[(NA * TM + r) * 32 + koff];
            if constexpr (NB > 1) b_l[ni] = *(const f16x8*)&sm[(NA * TM + TN + r) * 32 + koff];
        }
        #pragma unroll
        for (int mi = 0; mi < 4; ++mi) {
            #pragma unroll
            for (int ni = 0; ni < 4; ++ni) {
                acc[mi][ni] = __builtin_amdgcn_mfma_f32_16x16x32_f16(a_h[mi], b_h[ni], acc[mi][ni], 0, 0, 0);
                if constexpr (NA > 1)
                    acc[mi][ni] = __builtin_amdgcn_mfma_f32_16x16x32_f16(a_l[mi], b_h[ni], acc[mi][ni], 0, 0, 0);
                if constexpr (NB > 1)
                    acc[mi][ni] = __builtin_amdgcn_mfma_f32_16x16x32_f16(a_h[mi], b_l[ni], acc[mi][ni], 0, 0, 0);
            }
        }
        __syncthreads();
    }

    // epilogue: C/D layout col=lane&15, row=(lane>>4)*4+reg [m89-verified]
    const int rbase = (lane >> 4) * 4, ccol = lane & 15;

    if constexpr (MODE == 2) {
        const size_t sb = (size_t)blockIdx.z * 2048 * 1024;
        #pragma unroll
        for (int mi = 0; mi < 4; ++mi)
            #pragma unroll
            for (int r = 0; r < 4; ++r) {
                const int rowg = m0 + wm + mi * 16 + rbase + r;
                const float cm = *holec(holes, (int)blockIdx.z * 2048 + rowg);
                const float* sv = suffVT + sb + (size_t)rowg * 1024;
                #pragma unroll
                for (int ni = 0; ni < 4; ++ni)
                    acc[mi][ni][r] += cm * sv[n0 + wn + ni * 16 + ccol];
            }
    }

    if constexpr (OUTK == 0) {
        float* C = (float*)Cv + sC * blockIdx.z;
        #pragma unroll
        for (int ni = 0; ni < 4; ++ni) {
            const int col = n0 + wn + ni * 16 + ccol;
            const float bv = bias ? bias[col] : 0.0f;
            #pragma unroll
            for (int mi = 0; mi < 4; ++mi)
                #pragma unroll
                for (int r = 0; r < 4; ++r)
                    C[(size_t)(m0 + wm + mi * 16 + rbase + r) * ldc + col] = acc[mi][ni][r] + bv;
        }
    } else {
        f16* Ch = (f16*)Cv  + sC * blockIdx.z;
        f16* Cl = (f16*)Cl2 + sC * blockIdx.z;
        #pragma unroll
        for (int ni = 0; ni < 4; ++ni) {
            const int col = n0 + wn + ni * 16 + ccol;
            #pragma unroll
            for (int mi = 0; mi < 4; ++mi)
                #pragma unroll
                for (int r = 0; r < 4; ++r) {
                    const size_t idx = (size_t)(m0 + wm + mi * 16 + rbase + r) * ldc + col;
                    const float x = acc[mi][ni][r];
                    const f16 h = (f16)x;
                    Ch[idx] = h;
                    Cl[idx] = (f16)(x - (float)h);
                }
        }
    }
}

// ---------- softmax -> P (zero-padded to 256-granular) + cmask ----------
// real (t<=s): exp(x/32+1e-13-m)/Z ; padded (s<t<Vs'): 0 ; beyond Vs': unread
// by PV (K=(bm+1)*256 == min Vs' in tile). cmask[b,s]=exp(-1e-13-m)/Z.
__global__ __launch_bounds__(256)
void softmax_p2(const float* __restrict__ scores, f16* __restrict__ P,
                float* __restrict__ holes)
{
    const int s = blockIdx.x, b = blockIdx.y;
    const float* srow = scores + ((size_t)b * 2048 + s) * 2048;
    f16* prow = P + ((size_t)b * 2048 + s) * 2048;
    const int tid = threadIdx.x, c0 = tid * 8;
    const int Vs = ((s >> 8) + 1) << 8;   // 256-granular write extent (PV K-match)
    const int lane = tid & 63, wv = tid >> 6;

    float v[8];
    const bool have = c0 < Vs;
    float mloc = -3.4e38f;
    if (have) {
        // QK wrote scores on [0, Vs') (256-wide tiles); we only READ col <= s.
        float4 x0 = *(const float4*)(srow + c0);
        float4 x1 = *(const float4*)(srow + c0 + 4);
        const float xs[8] = {x0.x, x0.y, x0.z, x0.w, x1.x, x1.y, x1.z, x1.w};
        #pragma unroll
        for (int j = 0; j < 8; ++j) {
            const int col = c0 + j;
            if (col <= s) { v[j] = fmaf(xs[j], 0.03125f, 1e-13f); mloc = fmaxf(mloc, v[j]); }
            else v[j] = 0.0f;
        }
    }
    #pragma unroll
    for (int off = 1; off < 64; off <<= 1) mloc = fmaxf(mloc, __shfl_xor(mloc, off));
    __shared__ float redm[4], redz[4];
    if (lane == 0) redm[wv] = mloc;
    __syncthreads();
    float m = fmaxf(fmaxf(redm[0], redm[1]), fmaxf(redm[2], redm[3]));
    if (s < 2047) m = fmaxf(m, -1e-13f);  // masked entries participate in max

    float zloc = 0.0f;
    if (have) {
        #pragma unroll
        for (int j = 0; j < 8; ++j) {
            const int col = c0 + j;
            if (col <= s) { v[j] = expf(v[j] - m); zloc += v[j]; }
        }
    }
    #pragma unroll
    for (int off = 1; off < 64; off <<= 1) zloc += __shfl_xor(zloc, off);
    if (lane == 0) redz[wv] = zloc;
    __syncthreads();
    const float em = expf(-1e-13f - m);
    const float Z = redz[0] + redz[1] + redz[2] + redz[3] + (float)(2047 - s) * em;
    const float inv = 1.0f / Z;

    if (have) {
        f16x8 outv;
        #pragma unroll
        for (int j = 0; j < 8; ++j) {
            const int col = c0 + j;
            outv[j] = (col <= s) ? (f16)(v[j] * inv) : (f16)0.0f;
        }
        *(f16x8*)(prow + c0) = outv;
    }
    if (tid == 0) *hole(holes, b * 2048 + s) = em * inv;
}

// ================== fallback kernels (f32 in, bf16 split, reg-staged) ==================
__device__ __forceinline__ void split4b(const float4 v, bf16x4& h, bf16x4& l) {
    __bf16 h0 = (__bf16)v.x; float r0 = v.x - (float)h0;
    __bf16 h1 = (__bf16)v.y; float r1 = v.y - (float)h1;
    __bf16 h2 = (__bf16)v.z; float r2 = v.z - (float)h2;
    __bf16 h3 = (__bf16)v.w; float r3 = v.w - (float)h3;
    h[0] = h0; h[1] = h1; h[2] = h2; h[3] = h3;
    l[0] = (__bf16)r0; l[1] = (__bf16)r1; l[2] = (__bf16)r2; l[3] = (__bf16)r3;
}

__global__ __launch_bounds__(256)
void gemm_bt_split(const float* __restrict__ A, int lda, size_t strideA,
                   const float* __restrict__ B, int ldb, size_t strideB,
                   float* __restrict__ C, int ldc, size_t strideC,
                   int K, const float* __restrict__ bias)
{
    constexpr int LDT = 48;
    __shared__ __attribute__((aligned(16))) __bf16 Ah[128 * LDT];
    __shared__ __attribute__((aligned(16))) __bf16 Al[128 * LDT];
    __shared__ __attribute__((aligned(16))) __bf16 Bh[128 * LDT];
    __shared__ __attribute__((aligned(16))) __bf16 Bl[128 * LDT];
    const int tid = threadIdx.x;
    const int m0 = blockIdx.y * 128, n0 = blockIdx.x * 128;
    const float* Ab = A + strideA * blockIdx.z + (size_t)m0 * lda;
    const float* Bb = B + strideB * blockIdx.z + (size_t)n0 * ldb;
    const int lane = tid & 63, wid = tid >> 6;
    const int wm = (wid >> 1) * 64, wn = (wid & 1) * 64;
    const int fr = lane & 15, koff = (lane >> 4) << 3;
    f32x4 acc[4][4] = {};
    for (int k0 = 0; k0 < K; k0 += 32) {
        __syncthreads();
        #pragma unroll
        for (int i = 0; i < 4; ++i) {
            int f4 = tid + 256 * i, row = f4 >> 3, c4 = (f4 & 7) << 2;
            float4 va = *(const float4*)(Ab + (size_t)row * lda + (k0 + c4));
            bf16x4 h, l; split4b(va, h, l);
            *(bf16x4*)&Ah[row * LDT + c4] = h; *(bf16x4*)&Al[row * LDT + c4] = l;
            float4 vb = *(const float4*)(Bb + (size_t)row * ldb + (k0 + c4));
            split4b(vb, h, l);
            *(bf16x4*)&Bh[row * LDT + c4] = h; *(bf16x4*)&Bl[row * LDT + c4] = l;
        }
        __syncthreads();
        bf16x8 ah[4], al[4], bh[4], bl[4];
        #pragma unroll
        for (int mi = 0; mi < 4; ++mi) {
            int r = wm + mi * 16 + fr;
            ah[mi] = *(const bf16x8*)&Ah[r * LDT + koff];
            al[mi] = *(const bf16x8*)&Al[r * LDT + koff];
        }
        #pragma unroll
        for (int ni = 0; ni < 4; ++ni) {
            int r = wn + ni * 16 + fr;
            bh[ni] = *(const bf16x8*)&Bh[r * LDT + koff];
            bl[ni] = *(const bf16x8*)&Bl[r * LDT + koff];
        }
        #pragma unroll
        for (int mi = 0; mi < 4; ++mi)
            #pragma unroll
            for (int ni = 0; ni < 4; ++ni) {
                acc[mi][ni] = __builtin_amdgcn_mfma_f32_16x16x32_bf16(ah[mi], bh[ni], acc[mi][ni], 0, 0, 0);
                acc[mi][ni] = __builtin_amdgcn_mfma_f32_16x16x32_bf16(al[mi], bh[ni], acc[mi][ni], 0, 0, 0);
                acc[mi][ni] = __builtin_amdgcn_mfma_f32_16x16x32_bf16(ah[mi], bl[ni], acc[mi][ni], 0, 0, 0);
            }
    }
    float* Cb = C + strideC * blockIdx.z;
    const int rbase = (lane >> 4) * 4, ccol = lane & 15;
    #pragma unroll
    for (int ni = 0; ni < 4; ++ni) {
        int col = n0 + wn + ni * 16 + ccol;
        float bv = bias ? bias[col] : 0.0f;
        #pragma unroll
        for (int mi = 0; mi < 4; ++mi)
            #pragma unroll
            for (int r = 0; r < 4; ++r)
                Cb[(size_t)(m0 + wm + mi * 16 + rbase + r) * ldc + col] = acc[mi][ni][r] + bv;
    }
}

__global__ __launch_bounds__(256)
void softmax_causal(float* __restrict__ P, int S)
{
    const int row = blockIdx.x;
    float* p = P + ((size_t)blockIdx.y * S + row) * (size_t)S;
    const int tid = threadIdx.x, lane = tid & 63, wid = tid >> 6;
    float v[8];
    float4 x0 = *(const float4*)(p + tid * 4);
    float4 x1 = *(const float4*)(p + 1024 + tid * 4);
    const float xs[8] = {x0.x, x0.y, x0.z, x0.w, x1.x, x1.y, x1.z, x1.w};
    #pragma unroll
    for (int j = 0; j < 8; ++j) {
        int col = (j < 4) ? (tid * 4 + j) : (1024 + tid * 4 + (j - 4));
        v[j] = (col > row) ? -1e-13f : fmaf(xs[j], 0.03125f, 1e-13f);
    }
    float m = v[0];
    #pragma unroll
    for (int j = 1; j < 8; ++j) m = fmaxf(m, v[j]);
    #pragma unroll
    for (int off = 1; off < 64; off <<= 1) m = fmaxf(m, __shfl_xor(m, off));
    __shared__ float red[8];
    if (lane == 0) red[wid] = m;
    __syncthreads();
    m = fmaxf(fmaxf(red[0], red[1]), fmaxf(red[2], red[3]));
    float sm = 0.0f;
    #pragma unroll
    for (int j = 0; j < 8; ++j) { v[j] = expf(v[j] - m); sm += v[j]; }
    #pragma unroll
    for (int off = 1; off < 64; off <<= 1) sm += __shfl_xor(sm, off);
    if (lane == 0) red[4 + wid] = sm;
    __syncthreads();
    sm = red[4] + red[5] + red[6] + red[7];
    const float inv = 1.0f / sm;
    float4 o0, o1;
    o0.x = v[0] * inv; o0.y = v[1] * inv; o0.z = v[2] * inv; o0.w = v[3] * inv;
    o1.x = v[4] * inv; o1.y = v[5] * inv; o1.z = v[6] * inv; o1.w = v[7] * inv;
    *(float4*)(p + tid * 4) = o0;
    *(float4*)(p + 1024 + tid * 4) = o1;
}

// ---------- launch ----------
extern "C" void kernel_launch(void* const* d_in, const int* in_sizes, int n_in,
                              void* d_out, int out_size, void* d_ws, size_t ws_size,
                              hipStream_t stream)
{
    const float* Q  = (const float*)d_in[0];   // [B,S,D]
    const float* Km = (const float*)d_in[1];   // [B,S,D]
    const float* V  = (const float*)d_in[2];   // [B,D,S]
    const float* W  = (const float*)d_in[3];   // [E,D]
    const float* bv = (const float*)d_in[4];   // [E]
    float* out = (float*)d_out;                // [B,S,E]

    constexpr int B = 4, S = 2048, D = 1024, E = 1024;
    const dim3 blk(256), blk5(512);
    const size_t MB = 1u << 20;

    if (ws_size >= 164 * MB) {
        char* w8 = (char*)d_ws;
        float* scores = (float*)w8;                       // [0,64)MB f32 (holes: cmask+partials)
        f16* attn_h   = (f16*)(w8 + 32 * MB);             // [32,48) over dead scores
        f16* attn_l   = (f16*)(w8 + 48 * MB);             // [48,64)
        f16* Qh = (f16*)(w8 + 64 * MB);                   // [64,80)
        f16* Ql = (f16*)(w8 + 80 * MB);                   // [80,96)
        f16* P  = (f16*)(w8 + 64 * MB);                   // [64,96) overlays Qh/Ql (dead after QK)
        f16* Kh = (f16*)(w8 + 96 * MB);
        f16* Kl = (f16*)(w8 + 112 * MB);
        float* suffVT = (float*)(w8 + 96 * MB);           // [96,128) overlays Kh/Kl (dead after QK)
        f16* Vh = (f16*)(w8 + 128 * MB);
        f16* Vl = (f16*)(w8 + 144 * MB);
        f16* Wh = (f16*)(w8 + 160 * MB);                  // 2MB
        f16* Wl = (f16*)(w8 + 162 * MB);                  // 2MB

        split_f32_to_f16<<<2048, blk, 0, stream>>>(Q,  Qh, Ql, B * S * D / 4);
        split_f32_to_f16<<<2048, blk, 0, stream>>>(Km, Kh, Kl, B * S * D / 4);
        split_f32_to_f16<<<2048, blk, 0, stream>>>(V,  Vh, Vl, B * D * S / 4);
        split_f32_to_f16<<<512,  blk, 0, stream>>>(W,  Wh, Wl, E * D / 4);
        suffv_pass1<<<dim3(D / 256, 8, B), blk, 0, stream>>>(V, scores);

        // 1) scores = Q.K^T, causal tiles 128x256 (3-term split). 72 tiles/batch.
        gemm3<2, 2, 0, 1, 128, 256><<<dim3(72, 1, B), blk5, 0, stream>>>(
            Qh, Ql, D, (size_t)S * D, Kh, Kl, D, (size_t)S * D,
            scores, nullptr, S, (size_t)S * S, D, nullptr, nullptr, nullptr);
        // 2) softmax -> P zero-padded to 256-granular + cmask
        softmax_p2<<<dim3(S, B), blk, 0, stream>>>(scores, P, scores);
        // suffix sums (over dead Kh/Kl)
        suffv_pass2<<<dim3(D / 256, 8, B), blk, 0, stream>>>(V, scores, suffVT);
        // 3) attn = P.V^T + cmask*suffV, tiles 256x128 (P 1-plane on wide side)
        gemm3<1, 2, 2, 2, 256, 128><<<dim3(D / 128, S / 256, B), blk5, 0, stream>>>(
            P, nullptr, S, (size_t)S * S, Vh, Vl, S, (size_t)D * S,
            attn_h, attn_l, D, (size_t)S * D, S, nullptr, scores, suffVT);
        // 4) out = attn.W^T + b, tiles 128x256 (3-term)
        gemm3<2, 2, 0, 0, 128, 256><<<dim3(E / 256, (B * S) / 128, 1), blk5, 0, stream>>>(
            attn_h, attn_l, D, 0, Wh, Wl, D, 0, out, nullptr, E, 0, D, bv,
            nullptr, nullptr);
    } else if (ws_size >= ((size_t)B * S * S + (size_t)B * S * D) * sizeof(float)) {
        float* scores = (float*)d_ws;
        float* attn   = scores + (size_t)B * S * S;
        gemm_bt_split<<<dim3(S / 128, S / 128, B), blk, 0, stream>>>(
            Q, D, (size_t)S * D, Km, D, (size_t)S * D, scores, S, (size_t)S * S, D, nullptr);
        softmax_causal<<<dim3(S, B), blk, 0, stream>>>(scores, S);
        gemm_bt_split<<<dim3(D / 128, S / 128, B), blk, 0, stream>>>(
            scores, S, (size_t)S * S, V, S, (size_t)D * S, attn, D, (size_t)S * D, S, nullptr);
        gemm_bt_split<<<dim3(E / 128, (B * S) / 128, 1), blk, 0, stream>>>(
            attn, D, 0, W, D, 0, out, E, 0, D, bv);
    } else {
        float* sc   = (float*)d_ws;
        float* attn = sc + (size_t)S * S;
        for (int b = 0; b < B; ++b) {
            const float* Qb = Q  + (size_t)b * S * D;
            const float* Kb = Km + (size_t)b * S * D;
            const float* Vb = V  + (size_t)b * D * S;
            float* outb = out + (size_t)b * S * E;
            gemm_bt_split<<<dim3(S / 128, S / 128, 1), blk, 0, stream>>>(
                Qb, D, 0, Kb, D, 0, sc, S, 0, D, nullptr);
            softmax_causal<<<dim3(S, 1), blk, 0, stream>>>(sc, S);
            gemm_bt_split<<<dim3(D / 128, S / 128, 1), blk, 0, stream>>>(
                sc, S, 0, Vb, S, 0, attn, D, 0, S, nullptr);
            gemm_bt_split<<<dim3(E / 128, S / 128, 1), blk, 0, stream>>>(
                attn, D, 0, W, D, 0, outb, E, 0, D, bv);
        }
    }
}